// Round 4
// baseline (250.059 us; speedup 1.0000x reference)
//
#include <hip/hip_runtime.h>
#include <math.h>

// ---------------------------------------------------------------------------
// TimeAttender: S=2048, B=32, D=512, K=147
// out = concat(applied [B*D], norm_w [B*S])
//
// Math notes:
//  * prev_probs normalizer and softmax Z cancel in
//      norm_w = adj * exp(w) / sum_s(adj * exp(w))
//  * w is a cosine similarity in [-1,1] -> exp(w) in [0.37, 2.72]:
//    no max-subtraction needed; apply pass is single-pass over e.
//  * w = dot * rsq(sq) replaces sqrt+IEEE-div (v_rsq, rel err ~1e-6).
//    sq==0 guard reproduces reference zero-norm path.
//  * Round-2 lesson (-55 us regression): last-block-done fusion is a trap —
//    per-block __threadfence() = full-L2 writeback+invalidate serialized
//    every wave. Combine stays a separate kernel. Do NOT re-fuse.
//  * Round-3 lesson: occupancy 4->8 waves/SIMD, 2-row ILP batching, CH
//    changes were all NEUTRAL (main pinned at ~60 us = 2.5 TB/s read).
//    VALU/LDS/latency models say ~22 us -> main is bound by its MEMORY
//    ACCESS PATTERN: e[s,b,d] has b-stride 2 KB, s-stride 64 KB; walking s
//    for fixed b touches 2 KB per 64 KB stripe.
//  * This round: block = (s-chunk, 4 consecutive b). The 4 waves read
//    e[s, b..b+3, :] = 8 KB CONTIGUOUS per iteration; blockIdx.x sweeps s.
//    Per-wave partials (no cross-b block reduce; main has zero LDS/barriers);
//    ns precomputed in front so main's prologue is two L2 loads.
// ---------------------------------------------------------------------------

__device__ __forceinline__ float wave_sum(float v) {
    for (int off = 32; off; off >>= 1) v += __shfl_xor(v, off);
    return v;
}

// ---------------------------------------------------------------------------
// K1: grid (1 + S/256, B), block 256. Role split on blockIdx.x:
//   bx == 0 : ns[b,:] = normalize(state[b,:] @ W^T + bias)  (safe-norm)
//   bx >= 1 : adj[b, s] = relu(conv1d_same(prev[b,:], cw)[s] + cb0)
// ---------------------------------------------------------------------------
__global__ __launch_bounds__(256) void front_kernel(
    const float* __restrict__ state, const float* __restrict__ W,
    const float* __restrict__ bias, const float* __restrict__ prev,
    const float* __restrict__ cw, const float* __restrict__ cb,
    float* __restrict__ ns, float* __restrict__ adj,
    int S, int D, int K) {
    __shared__ __align__(16) float smem[1024];
    __shared__ float red[4];
    int b = blockIdx.y;
    int t = threadIdx.x;
    int lane = t & 63, wv = t >> 6;

    if (blockIdx.x == 0) {
        // ---- linear + normalize: 256 threads x 2 dots of length 512 ----
        if (t < D / 4)
            ((float4*)smem)[t] = ((const float4*)(state + (size_t)b * D))[t];
        __syncthreads();
        const float4* sv = (const float4*)smem;
        float acc0 = bias[t];
        float acc1 = bias[t + 256];
        const float4* W0 = (const float4*)(W + (size_t)t * D);
        const float4* W1 = (const float4*)(W + (size_t)(t + 256) * D);
#pragma unroll 8
        for (int k = 0; k < 128; ++k) {
            float4 s4 = sv[k];
            float4 w0 = W0[k];
            float4 w1 = W1[k];
            acc0 += w0.x * s4.x + w0.y * s4.y + w0.z * s4.z + w0.w * s4.w;
            acc1 += w1.x * s4.x + w1.y * s4.y + w1.z * s4.z + w1.w * s4.w;
        }
        // block-wide sum of squares over the 512 outputs
        float sq = acc0 * acc0 + acc1 * acc1;
        sq = wave_sum(sq);
        if (lane == 0) red[wv] = sq;
        __syncthreads();
        float tot = red[0] + red[1] + red[2] + red[3];
        // safe-norm: ref divides by 1e-10 when norm==0 -> ns = 0 either way
        float inv = (tot > 0.f) ? __builtin_amdgcn_rsqf(tot) : 0.f;
        ns[(size_t)b * D + t] = acc0 * inv;
        ns[(size_t)b * D + t + 256] = acc1 * inv;
    } else {
        // ---- conv part ----
        int s0 = (blockIdx.x - 1) * 256;
        int pad = K / 2;
        int seglen = 256 + K - 1;
        float* seg = smem;            // seglen floats (<= 256+255)
        float* wk = smem + 512;       // K floats (<= 256)
        for (int i = t; i < seglen; i += 256) {
            int s = s0 - pad + i;
            seg[i] = (s >= 0 && s < S) ? prev[(size_t)b * S + s] : 0.f;
        }
        for (int j = t; j < K; j += 256) wk[j] = cw[j];
        __syncthreads();
        float y = cb[0];
        for (int j = 0; j < K; ++j) y += seg[t + j] * wk[j];
        adj[(size_t)b * S + s0 + t] = fmaxf(y, 0.f);
    }
}

// ---------------------------------------------------------------------------
// K2 (main, single e pass, streaming layout): grid (S/CH, B/4), block 256.
// Wave w of block (sx, by) owns b = by*4+w, s in [sx*CH, sx*CH+CH):
//   - per iteration the BLOCK reads e[s, 4b-group, :] = 8 KB contiguous
//   - per row PAIR: 4 interleaved shfl butterflies (dot,sq x 2 rows),
//     coef = adj*exp(dot*rsq(sq)); acc += coef*row; z += coef; u <- coef
//   - per-wave partial store (no LDS, no barriers in this kernel)
// ---------------------------------------------------------------------------
__global__ __launch_bounds__(256) void main_kernel(
    const float* __restrict__ e, const float* __restrict__ ns,
    const float* __restrict__ adj, float* __restrict__ partial,
    float* __restrict__ zbuf, float* __restrict__ u,
    int S, int B, int D) {
    constexpr int CH = 8;
    int wave = threadIdx.x >> 6;
    int lane = threadIdx.x & 63;
    int b = blockIdx.y * 4 + wave;
    int sx = blockIdx.x;
    int s0 = sx * CH;

    const float4* ns4 = (const float4*)(ns + (size_t)b * D);
    float4 ns0 = ns4[lane];
    float4 ns1 = ns4[lane + 64];

    // chunk's adj values (uniform per row): one shfl per row off the chain
    float adjv = (lane < CH) ? adj[(size_t)b * S + s0 + lane] : 0.f;

    float4 acc0 = {0.f, 0.f, 0.f, 0.f};
    float4 acc1 = {0.f, 0.f, 0.f, 0.f};
    float z = 0.f;

    const float4* row4 = (const float4*)(e + ((size_t)s0 * B + b) * D);
    size_t rstride = (size_t)B * D / 4;   // float4 stride between s rows

#pragma unroll 2
    for (int i = 0; i < CH; i += 2) {
        float4 xa0 = row4[lane];
        float4 xa1 = row4[lane + 64];
        float4 xb0 = row4[rstride + lane];
        float4 xb1 = row4[rstride + lane + 64];
        float ava = __shfl(adjv, i);
        float avb = __shfl(adjv, i + 1);
        float dota = xa0.x * ns0.x + xa0.y * ns0.y + xa0.z * ns0.z + xa0.w * ns0.w
                   + xa1.x * ns1.x + xa1.y * ns1.y + xa1.z * ns1.z + xa1.w * ns1.w;
        float sqa  = xa0.x * xa0.x + xa0.y * xa0.y + xa0.z * xa0.z + xa0.w * xa0.w
                   + xa1.x * xa1.x + xa1.y * xa1.y + xa1.z * xa1.z + xa1.w * xa1.w;
        float dotb = xb0.x * ns0.x + xb0.y * ns0.y + xb0.z * ns0.z + xb0.w * ns0.w
                   + xb1.x * ns1.x + xb1.y * ns1.y + xb1.z * ns1.z + xb1.w * ns1.w;
        float sqb  = xb0.x * xb0.x + xb0.y * xb0.y + xb0.z * xb0.z + xb0.w * xb0.w
                   + xb1.x * xb1.x + xb1.y * xb1.y + xb1.z * xb1.z + xb1.w * xb1.w;
#pragma unroll
        for (int off = 32; off; off >>= 1) {   // 4 independent chains: ILP
            dota += __shfl_xor(dota, off);
            dotb += __shfl_xor(dotb, off);
            sqa  += __shfl_xor(sqa, off);
            sqb  += __shfl_xor(sqb, off);
        }
        float ra = (sqa > 0.f) ? __builtin_amdgcn_rsqf(sqa) : 0.f;
        float rb = (sqb > 0.f) ? __builtin_amdgcn_rsqf(sqb) : 0.f;
        float coefa = ava * __expf(dota * ra);
        float coefb = avb * __expf(dotb * rb);
        if (lane == 0)
            *((float2*)(u + (size_t)b * S + s0 + i)) = make_float2(coefa, coefb);
        acc0.x += coefa * xa0.x + coefb * xb0.x;
        acc0.y += coefa * xa0.y + coefb * xb0.y;
        acc0.z += coefa * xa0.z + coefb * xb0.z;
        acc0.w += coefa * xa0.w + coefb * xb0.w;
        acc1.x += coefa * xa1.x + coefb * xb1.x;
        acc1.y += coefa * xa1.y + coefb * xb1.y;
        acc1.z += coefa * xa1.z + coefb * xb1.z;
        acc1.w += coefa * xa1.w + coefb * xb1.w;
        z += coefa + coefb;
        row4 += 2 * rstride;
    }

    // per-wave partial: partial[sx][b][:]
    float4* p4 = (float4*)(partial + ((size_t)sx * B + b) * D);
    p4[lane] = acc0;
    p4[lane + 64] = acc1;
    if (lane == 0) zbuf[(size_t)sx * B + b] = z;
}

// ---------------------------------------------------------------------------
// K3: grid (4, B), block 256. Block (q,b):
//   Z = sum_c zbuf[c][b]  (NPART=256: one per thread, block reduce)
//   applied[b, q*128 .. +128) = sum_c partial[c][b][slice] / Z
//   norm_w[b, q*512 .. +512) = u[...] / Z
// ---------------------------------------------------------------------------
__global__ __launch_bounds__(256) void combine_kernel(
    const float* __restrict__ partial, const float* __restrict__ zbuf,
    const float* __restrict__ u, float* __restrict__ applied,
    float* __restrict__ norm_w, int S, int B, int D, int NPART) {
    int q = blockIdx.x;       // 0..3
    int b = blockIdx.y;
    int t = threadIdx.x;
    __shared__ __align__(16) float4 red4[8][32];
    __shared__ float zred[4];
    __shared__ float zsh;

    // Z reduce: one zbuf entry per thread (NPART <= 256), block reduce
    float zt = (t < NPART) ? zbuf[(size_t)t * B + b] : 0.f;
    zt = wave_sum(zt);
    if ((t & 63) == 0) zred[t >> 6] = zt;

    // applied quarter: 32 float4 columns, 8-way chunk strata across threads
    int c2 = t >> 5;          // 0..7
    int di = t & 31;          // 0..31
    int d4 = q * 32 + di;     // float4 index into D/4 = 128
    const float4* p4 = (const float4*)partial;
    float4 a = {0.f, 0.f, 0.f, 0.f};
    for (int cix = c2; cix < NPART; cix += 8) {
        float4 x = p4[((size_t)cix * B + b) * (D >> 2) + d4];
        a.x += x.x; a.y += x.y; a.z += x.z; a.w += x.w;
    }
    red4[c2][di] = a;
    __syncthreads();
    if (t == 0) zsh = 1.f / (zred[0] + zred[1] + zred[2] + zred[3]);
    __syncthreads();
    float inv = zsh;
    if (t < 32) {
        float4 s = red4[0][t];
#pragma unroll
        for (int j = 1; j < 8; ++j) {
            float4 x = red4[j][t];
            s.x += x.x; s.y += x.y; s.z += x.z; s.w += x.w;
        }
        s.x *= inv; s.y *= inv; s.z *= inv; s.w *= inv;
        ((float4*)(applied + (size_t)b * D))[q * 32 + t] = s;
    }

    // norm_w quarter: 128 float4 per q-slice
    const float4* u4 = (const float4*)(u + (size_t)b * S);
    float4* nw4 = (float4*)(norm_w + (size_t)b * S);
    if (t < 128) {
        int idx = q * (S >> 4) + t;   // S/4 float4 per b, quarter = S/16
        float4 x = u4[idx];
        x.x *= inv; x.y *= inv; x.z *= inv; x.w *= inv;
        nw4[idx] = x;
    }
}

extern "C" void kernel_launch(void* const* d_in, const int* in_sizes, int n_in,
                              void* d_out, int out_size, void* d_ws, size_t ws_size,
                              hipStream_t stream) {
    const float* enc   = (const float*)d_in[0];  // [S,B,D]
    const float* state = (const float*)d_in[1];  // [B,D]
    const float* prev  = (const float*)d_in[2];  // [B,S]
    const float* W     = (const float*)d_in[3];  // [D,D]
    const float* bias  = (const float*)d_in[4];  // [D]
    const float* cw    = (const float*)d_in[5];  // [K]
    const float* cb    = (const float*)d_in[6];  // [1]

    const int S = in_sizes[0] / in_sizes[1];   // 2048
    const int B = in_sizes[2] / S;             // 32
    const int D = in_sizes[1] / B;             // 512
    const int K = in_sizes[5];                 // 147

    float* out     = (float*)d_out;
    float* applied = out;                    // B*D
    float* norm_w  = out + (size_t)B * D;    // B*S

    const int CH = 8;              // s-rows per wave (matches kernel constexpr)
    const int NPART = S / CH;      // 256 per-wave partials per batch row

    float* ws       = (float*)d_ws;
    float* nsbuf    = ws;                            // B*D
    float* adj      = nsbuf + (size_t)B * D;         // B*S
    float* u        = adj + (size_t)B * S;           // B*S
    float* zbuf     = u + (size_t)B * S;             // NPART*B
    float* partial  = zbuf + (size_t)NPART * B;      // NPART*B*D (16.8 MB)

    front_kernel<<<dim3(1 + S / 256, B), 256, 0, stream>>>(
        state, W, bias, prev, cw, cb, nsbuf, adj, S, D, K);
    main_kernel<<<dim3(S / CH, B / 4), 256, 0, stream>>>(
        enc, nsbuf, adj, partial, zbuf, u, S, B, D);
    combine_kernel<<<dim3(4, B), 256, 0, stream>>>(
        partial, zbuf, u, applied, norm_w, S, B, D, NPART);
}